// Round 5
// baseline (376.060 us; speedup 1.0000x reference)
//
#include <hip/hip_runtime.h>

// R13 = occupancy fix with corrected register model.
// Fitted across R8-R12: waves/SIMD = pow2floor(512 / (archVGPR + accVGPR)),
// and rocprof VGPR_Count reports ARCH ONLY. R12 = 84 arch + (A-frags 48 +
// acc 12) = 144 combined -> 2 waves/SIMD (Occ 26%). Target combined <=128:
//  - A3 (3rd-level i8 fragments, 16 regs) -> LDS, own-lane write/read (no
//    barrier needed), ds_read_b128 per (nt,kt). A1/A2 stay in regs.
//  - zimg 4 buffers -> 2 (barrier per step; R7->R8 chunking was worth ~1%).
//    Ping-pong safe: GEMM(t) and the next write of parity t&1 (LIF1(t+2))
//    are separated by barrier(t+1) in every thread.
//  - fc defers by 1 step over the 4-slot z2 ring (slot t&3).
// LDS = 9792(zimg) + 4896(z2/overlay) + 4616(wf) + 3744(cur) + 16384(A3)
//     = 39.4 KB <= 40 KB -> 4 blocks/CU; grid 1024 = 4 blocks/CU exactly.
// Estimated combined ~120 -> 4 waves/SIMD -> 16 waves/CU (50%).
// Numerics identical to R8: 3-level nested i8, exact i32 acc.

#define NSTEPS 100
#define IMSTRIDE 272
#define NROW 18
#define ZIMG (NROW * IMSTRIDE)     // 4896 B per buffer; 2 buffers
#define Z2SLOT 1224                // u8 z2 per t-slot: 2 samples x 9 pos x 68

typedef __attribute__((ext_vector_type(4))) int i32x4;

// conv1 + 2x2 maxpool for one spike-row (sample, ic, y): 6 outputs
__device__ __forceinline__ void conv1_row(const float* __restrict__ xs,
                                          const float* __restrict__ w1s,
                                          float b1v, int y, float* cur) {
    float cr[2][12];
    #pragma unroll
    for (int rr = 0; rr < 2; ++rr) {
        const int cy = 2 * y + rr;
        #pragma unroll
        for (int cx = 0; cx < 12; ++cx) {
            float a = 0.f;
            #pragma unroll
            for (int ky = 0; ky < 4; ++ky)
            #pragma unroll
            for (int kx = 0; kx < 4; ++kx)
                a = fmaf(xs[(cy + ky) * 16 + cx + kx], w1s[ky * 4 + kx], a);
            cr[rr][cx] = a + b1v;
        }
    }
    #pragma unroll
    for (int px = 0; px < 6; ++px)
        cur[px] = fmaxf(fmaxf(cr[0][2 * px], cr[0][2 * px + 1]),
                        fmaxf(cr[1][2 * px], cr[1][2 * px + 1]));
}

// LIF1 step for one spike-row + sigma-permuted i8 scatter.
// pb = zimg_buffer_base + (9*sl + 3*y)*IMSTRIDE + 16*ic
__device__ __forceinline__ void lif1_row(float* v1, float* i1, const float* cur,
                                         unsigned char* pb, int ic, int y) {
    unsigned zb[6];
    #pragma unroll
    for (int xx = 0; xx < 6; ++xx) {
        const float vd = v1[xx] + 0.1f * (i1[xx] - v1[xx]);
        i1[xx] = i1[xx] * 0.8f + cur[xx];
        const bool sp = vd > 1.0f;
        v1[xx] = sp ? 0.0f : vd;
        zb[xx] = sp ? 1u : 0u;
    }
    const unsigned q0 = zb[0] | (zb[1] << 8) | (zb[2] << 16) | (zb[3] << 24);
    const unsigned q1 = zb[1] | (zb[2] << 8) | (zb[3] << 16) | (zb[4] << 24);
    const unsigned q2 = zb[2] | (zb[3] << 8) | (zb[4] << 16) | (zb[5] << 24);
    #pragma unroll
    for (int ky = 0; ky < 4; ++ky) {
        const int py = y - ky;
        if (0 <= py && py <= 2) {
            unsigned char* b = pb - ky * (3 * IMSTRIDE) + 4 * ((ky + ic) & 3);
            *(unsigned*)(b)                = q0;   // px = 0
            *(unsigned*)(b + IMSTRIDE)     = q1;   // px = 1
            *(unsigned*)(b + 2 * IMSTRIDE) = q2;   // px = 2
        }
    }
}

__global__ __launch_bounds__(256, 3)
void snn_kernel(const float* __restrict__ x,
                const float* __restrict__ w1,
                const float* __restrict__ b1,
                const float* __restrict__ w2,
                const float* __restrict__ b2,
                const float* __restrict__ wf,
                const float* __restrict__ bf,
                float* __restrict__ out, int B)
{
    __shared__ __align__(16) unsigned char s_im[2 * ZIMG];      // 9792 B
    __shared__ __align__(16) unsigned char s_ovl[4 * Z2SLOT];   // 4896 B
    __shared__ __align__(16) float s_wf[1154];                  // 4616 B
    __shared__ __align__(16) float s_cur[156 * 6];              // 3744 B
    __shared__ __align__(16) unsigned char s_a3[4 * 4096];      // 16384 B

    // overlay: s_x/w1/b1 are only live before the first barrier;
    // z2 slots are first written after it.
    float* const s_xf = (float*)s_ovl;                 // 2*256*4 = 2048 B
    float* const s_w1 = (float*)(s_ovl + 2048);        // 832 B
    float* const s_b1 = (float*)(s_ovl + 2880);        // 52 B
    unsigned char* const s_z2 = s_ovl;

    const int tid  = threadIdx.x;
    const int wave = tid >> 6, lane = tid & 63;
    const int quad = lane >> 4, col = lane & 15;

    // ---- stage x / w1 / b1 / wf / bf; zero both zimg buffers ----
    if (wave < 2)
        ((float4*)(s_xf + wave * 256))[lane] =
            ((const float4*)(x + (size_t)(blockIdx.x * 2 + wave) * 256))[lane];
    if (tid < 208) s_w1[tid] = w1[tid];
    if (tid < 13)  s_b1[tid] = b1[tid];
    for (int i = tid; i < 576; i += 256) {
        const int q = i >> 6, l = i & 63;
        ((float2*)s_wf)[i] = make_float2(wf[l * 9 + q], wf[576 + l * 9 + q]);
    }
    if (tid == 0) ((float2*)s_wf)[576] = make_float2(bf[0], bf[1]);
    for (int i = tid; i < 2 * ZIMG / 16; i += 256)
        ((uint4*)s_im)[i] = make_uint4(0, 0, 0, 0);
    __syncthreads();

    // ---- LIF1 row ownership: 156 rows = 2 samples * 13 ic * 6 y ----
    const bool rowv = tid < 156;
    int sA = 0, icA = 0, yA = 0;
    if (rowv) { sA = tid / 78; int r = tid - 78 * sA; icA = r / 6; yA = r - 6 * icA; }

    // conv1 output is constant over time: compute once, park in LDS
    // (own-thread write/read -> no barrier needed).
    if (rowv) {
        float cu[6];
        conv1_row(s_xf + sA * 256, s_w1 + icA * 16, s_b1[icA], yA, cu);
        float2* cp = (float2*)(s_cur + tid * 6);
        cp[0] = make_float2(cu[0], cu[1]);
        cp[1] = make_float2(cu[2], cu[3]);
        cp[2] = make_float2(cu[4], cu[5]);
    }
    float v1a[6], i1a[6];
    #pragma unroll
    for (int j = 0; j < 6; ++j) { v1a[j] = 0.f; i1a[j] = 0.f; }
    const int pbOffA = (9 * sA + 3 * yA) * IMSTRIDE + 16 * icA;

    // ---- A-fragments: per-row 3-level i8 split of w2 (sigma-permuted K) ----
    // A1/A2 stay in registers; A3 parks in LDS (own-lane region, no sync).
    unsigned char* const a3p = s_a3 + wave * 4096 + lane * 16;
    i32x4 A1[4], A2[4];
    float Mrow;
    {
        const float* wrow = w2 + (size_t)(wave * 16 + col) * 208;
        float M = 1e-20f;
        for (int k = 0; k < 208; ++k) M = fmaxf(M, fabsf(wrow[k]));
        Mrow = M;
        const float inv = 127.0f / M;
        const float q1s = M * (1.0f / 127.0f);
        const float q2s = M * (1.0f / (127.0f * 127.0f));
        #pragma unroll
        for (int kt = 0; kt < 4; ++kt) {
            i32x4 w1v = {0, 0, 0, 0}, w2v = {0, 0, 0, 0}, w3v = {0, 0, 0, 0};
            #pragma unroll
            for (int j = 0; j < 16; ++j) {
                const int kp = kt * 64 + quad * 16 + j;
                const int W = kp >> 2, kx = kp & 3;
                const int ic = W >> 2, ky = ((W & 3) - ic) & 3;
                const float w = (ic < 13) ? wrow[ic * 16 + ky * 4 + kx] : 0.f;
                const float b1f = rintf(w * inv);
                const float r1  = fmaf(b1f, -q1s, w);
                const float b2f = rintf(r1 * inv * 127.0f);
                const float r2  = fmaf(b2f, -q2s, r1);
                const float b3f = rintf(r2 * inv * 127.0f * 127.0f);
                const int wi = j >> 2, sh = (j & 3) * 8;
                w1v[wi] |= ((int)b1f & 0xFF) << sh;
                w2v[wi] |= ((int)b2f & 0xFF) << sh;
                w3v[wi] |= ((int)b3f & 0xFF) << sh;
            }
            A1[kt] = w1v; A2[kt] = w2v;
            *(i32x4*)(a3p + kt * 1024) = w3v;
        }
    }
    // only level-1 scale kept per-lane; levels 2/3 fold as compile-time consts
    float sc1[4];
    #pragma unroll
    for (int r = 0; r < 4; ++r)
        sc1[r] = __shfl(Mrow, quad * 4 + r) * (1.0f / 127.0f);

    float b2r[4];
    #pragma unroll
    for (int r = 0; r < 4; ++r) b2r[r] = b2[wave * 16 + quad * 4 + r];

    int bpo[2];        // byte offset of B-frag within a zimg buffer
    int zwo[2];        // byte offset of z2 write within a t-slot
    #pragma unroll
    for (int nt = 0; nt < 2; ++nt) {
        const int n = nt * 16 + col;
        const int nc = (n < 18) ? n : (n - 14);   // clamp: row stays valid
        bpo[nt] = nc * IMSTRIDE + quad * 16;
        const int slz = nc / 9, pos = nc - 9 * slz;
        zwo[nt] = slz * 612 + pos * 68 + wave * 16 + quad * 4;
    }

    float v2[8], i2[8];
    #pragma unroll
    for (int p = 0; p < 8; ++p) { v2[p] = 0.f; i2[p] = 0.f; }
    float v3a = 0.f, i3a = 0.f, v3b = 0.f, i3b = 0.f, sum0 = 0.f, sum1 = 0.f;

    const int sGf = blockIdx.x * 2 + (wave - 2);   // valid for waves 2,3
    float* outv = out + (size_t)2 * B;

    // One fc + LIF3 step from a z2 t-slot base (u8), storing v3_seq[tp].
    auto fc_step = [&](const unsigned char* zs, int tp) {
        float p0 = 0.f, p1 = 0.f;
        #pragma unroll
        for (int q = 0; q < 9; ++q) {
            const float z = (float)zs[q * 68 + lane];
            const float2 wv = ((const float2*)s_wf)[q * 64 + lane];
            p0 = fmaf(z, wv.x, p0);
            p1 = fmaf(z, wv.y, p1);
        }
        #pragma unroll
        for (int off = 32; off > 0; off >>= 1) {
            p0 += __shfl_xor(p0, off);
            p1 += __shfl_xor(p1, off);
        }
        const float2 bfv = ((const float2*)s_wf)[576];
        const float c3a = p0 + bfv.x, c3b = p1 + bfv.y;
        const float vd0 = v3a + 0.1f * (i3a - v3a);
        const float vd1 = v3b + 0.1f * (i3b - v3b);
        i3a = i3a * 0.8f + c3a;
        i3b = i3b * 0.8f + c3b;
        const bool q0 = vd0 > 1.0f, q1 = vd1 > 1.0f;
        v3a = q0 ? 0.0f : vd0;
        v3b = q1 ? 0.0f : vd1;
        sum0 += q0 ? 1.0f : 0.0f;
        sum1 += q1 ? 1.0f : 0.0f;
        if (lane == 0)
            *(float2*)(outv + (size_t)tp * 2 * B + 2 * sGf) = make_float2(v3a, v3b);
    };

    // ---- main loop: 1 barrier per step; zimg ping-pong; fc lags 1 step ----
    #pragma unroll 2
    for (int t = 0; t < NSTEPS; ++t) {
        unsigned char* zb = s_im + (t & 1) * ZIMG;
        if (rowv) {
            float cu[6];
            const float2* cp = (const float2*)(s_cur + tid * 6);
            const float2 ca = cp[0], cb = cp[1], cc2 = cp[2];
            cu[0] = ca.x; cu[1] = ca.y; cu[2] = cb.x;
            cu[3] = cb.y; cu[4] = cc2.x; cu[5] = cc2.y;
            lif1_row(v1a, i1a, cu, zb + pbOffA, icA, yA);
        }
        __syncthreads();                 // the only barrier per step

        // deferred fc (waves 2,3): step t-1 from z2 ring slot (t-1)&3
        if (t && wave >= 2)
            fc_step(s_z2 + ((t - 1) & 3) * Z2SLOT + (wave - 2) * 612, t - 1);

        // GEMM + LIF2 for step t: per n-tile, 3 chains live (12 acc regs)
        unsigned char* z2w = s_z2 + (t & 3) * Z2SLOT;
        #pragma unroll
        for (int nt = 0; nt < 2; ++nt) {
            i32x4 c1 = {0, 0, 0, 0}, c2 = c1, c3 = c1;
            #pragma unroll
            for (int kt = 0; kt < 4; ++kt) {
                const i32x4 Bv  = *(const i32x4*)(zb + bpo[nt] + kt * 64);
                const i32x4 A3v = *(const i32x4*)(a3p + kt * 1024);
                c1 = __builtin_amdgcn_mfma_i32_16x16x64_i8(A1[kt], Bv, c1, 0, 0, 0);
                c2 = __builtin_amdgcn_mfma_i32_16x16x64_i8(A2[kt], Bv, c2, 0, 0, 0);
                c3 = __builtin_amdgcn_mfma_i32_16x16x64_i8(A3v,    Bv, c3, 0, 0, 0);
            }
            unsigned zby[4];
            #pragma unroll
            for (int r = 0; r < 4; ++r) {
                const int p = nt * 4 + r;
                const float tt =
                    fmaf(1.0f / (127.0f * 127.0f), (float)c3[r],
                    fmaf(1.0f / 127.0f,            (float)c2[r],
                                                   (float)c1[r]));
                const float cur2 = fmaf(sc1[r], tt, b2r[r]);
                const float vd = v2[p] + 0.1f * (i2[p] - v2[p]);
                i2[p] = i2[p] * 0.8f + cur2;
                const bool sp = vd > 1.0f;
                v2[p] = sp ? 0.0f : vd;
                zby[r] = sp ? 1u : 0u;
            }
            const unsigned pk =
                zby[0] | (zby[1] << 8) | (zby[2] << 16) | (zby[3] << 24);
            if (nt == 0 || col < 2)
                *(unsigned*)(z2w + zwo[nt]) = pk;
        }
    }

    __syncthreads();
    if (wave >= 2) {   // final fc: step 99 from slot 3
        fc_step(s_z2 + ((NSTEPS - 1) & 3) * Z2SLOT + (wave - 2) * 612, NSTEPS - 1);
        if (lane == 0)
            *(float2*)(out + (size_t)2 * sGf) = make_float2(sum0, sum1);
    }
}

extern "C" void kernel_launch(void* const* d_in, const int* in_sizes, int n_in,
                              void* d_out, int out_size, void* d_ws, size_t ws_size,
                              hipStream_t stream)
{
    const float* x  = (const float*)d_in[0];
    const float* w1 = (const float*)d_in[1];
    const float* b1 = (const float*)d_in[2];
    const float* w2 = (const float*)d_in[3];
    const float* b2 = (const float*)d_in[4];
    const float* wf = (const float*)d_in[5];
    const float* bf = (const float*)d_in[6];
    float* out = (float*)d_out;

    const int B = in_sizes[0] / 256;     // x is [B,1,16,16]
    const int grid = B / 2;              // 2 samples per block

    hipLaunchKernelGGL(snn_kernel, dim3(grid), dim3(256), 0, stream,
                       x, w1, b1, w2, b2, wf, bf, out, B);
}

// Round 6
// 375.048 us; speedup vs baseline: 1.0027x; 1.0027x over previous
//
#include <hip/hip_runtime.h>

// R14 = widen the block, keep the grid: 384 threads (6 waves), 4 samples/block,
// grid = B/4 = 512 (one full round, 2 blocks/CU like R8).
// Occupancy model fitted R8-R13: waves/SIMD = pow2floor(512/combined) -- 136
// combined quantizes DOWN to 2 (R13's 26%). Instead of chasing combined<=128
// (LDS wall), raise waves/CU by widening: 2 blocks x 6 waves = 12 waves/CU =
// 3/SIMD, which needs combined <= 170 only.
//  - waves 0-3: GEMM (16 oc each, serial n-tile, 12 acc) + LIF1 + LIF2.
//  - waves 4-5: fc/LIF3 (2 samples each) + 28 LIF1 rows each -> fc off the
//    GEMM critical path; no double-row LIF1 stragglers (312 rows < 384 thr).
//  - R13 diet kept: A3->LDS, wf->LDS, cur1->LDS, folded scales, z2 u8 ring.
//  - 2 zimg buffers, 1 barrier/step (hazard-proof: GEMM(t) and LIF1(t+2)
//    separated by barrier(t+1) in every thread).
//  - s_setprio(1) around MFMA cluster: fc/GEMM wave role-split satisfies
//    T5's prerequisite (phase-diverse waves on the CU scheduler).
// LDS = 26112(zimg) + 9792(z2/overlay) + 16384(a3) + 7488(cur) + 4616(wf)
//     = 64392 B -> 2 blocks = 128.8 KB <= 160 ✓.
// __launch_bounds__(384,3): allocator cap 170 combined; est ~155. Tripwire:
// FETCH_SIZE explosion = spill.
// Numerics identical to R8/R13: 3-level nested i8, exact i32 acc.

#define NSTEPS 100
#define IMSTRIDE 272
#define NROW 48
#define ZIMG (NROW * IMSTRIDE)   // 13056 B per buffer; 2 buffers
#define Z2SLOT 2448              // u8 z2 per t-slot: 4 samples x 9 pos x 68

typedef __attribute__((ext_vector_type(4))) int i32x4;

// conv1 + 2x2 maxpool for one spike-row (sample, ic, y): 6 outputs
__device__ __forceinline__ void conv1_row(const float* __restrict__ xs,
                                          const float* __restrict__ w1s,
                                          float b1v, int y, float* cur) {
    float cr[2][12];
    #pragma unroll
    for (int rr = 0; rr < 2; ++rr) {
        const int cy = 2 * y + rr;
        #pragma unroll
        for (int cx = 0; cx < 12; ++cx) {
            float a = 0.f;
            #pragma unroll
            for (int ky = 0; ky < 4; ++ky)
            #pragma unroll
            for (int kx = 0; kx < 4; ++kx)
                a = fmaf(xs[(cy + ky) * 16 + cx + kx], w1s[ky * 4 + kx], a);
            cr[rr][cx] = a + b1v;
        }
    }
    #pragma unroll
    for (int px = 0; px < 6; ++px)
        cur[px] = fmaxf(fmaxf(cr[0][2 * px], cr[0][2 * px + 1]),
                        fmaxf(cr[1][2 * px], cr[1][2 * px + 1]));
}

// LIF1 step for one spike-row + sigma-permuted i8 scatter.
// pb = zimg_buffer_base + (9*sl + 3*y)*IMSTRIDE + 16*ic
__device__ __forceinline__ void lif1_row(float* v1, float* i1, const float* cur,
                                         unsigned char* pb, int ic, int y) {
    unsigned zb[6];
    #pragma unroll
    for (int xx = 0; xx < 6; ++xx) {
        const float vd = v1[xx] + 0.1f * (i1[xx] - v1[xx]);
        i1[xx] = i1[xx] * 0.8f + cur[xx];
        const bool sp = vd > 1.0f;
        v1[xx] = sp ? 0.0f : vd;
        zb[xx] = sp ? 1u : 0u;
    }
    const unsigned q0 = zb[0] | (zb[1] << 8) | (zb[2] << 16) | (zb[3] << 24);
    const unsigned q1 = zb[1] | (zb[2] << 8) | (zb[3] << 16) | (zb[4] << 24);
    const unsigned q2 = zb[2] | (zb[3] << 8) | (zb[4] << 16) | (zb[5] << 24);
    #pragma unroll
    for (int ky = 0; ky < 4; ++ky) {
        const int py = y - ky;
        if (0 <= py && py <= 2) {
            unsigned char* b = pb - ky * (3 * IMSTRIDE) + 4 * ((ky + ic) & 3);
            *(unsigned*)(b)                = q0;   // px = 0
            *(unsigned*)(b + IMSTRIDE)     = q1;   // px = 1
            *(unsigned*)(b + 2 * IMSTRIDE) = q2;   // px = 2
        }
    }
}

__global__ __launch_bounds__(384, 3)
void snn_kernel(const float* __restrict__ x,
                const float* __restrict__ w1,
                const float* __restrict__ b1,
                const float* __restrict__ w2,
                const float* __restrict__ b2,
                const float* __restrict__ wf,
                const float* __restrict__ bf,
                float* __restrict__ out, int B)
{
    __shared__ __align__(16) unsigned char s_im[2 * ZIMG];      // 26112 B
    __shared__ __align__(16) unsigned char s_ovl[4 * Z2SLOT];   // 9792 B
    __shared__ __align__(16) float s_wf[1154];                  // 4616 B
    __shared__ __align__(16) float s_cur[312 * 6];              // 7488 B
    __shared__ __align__(16) unsigned char s_a3[4 * 4096];      // 16384 B

    // overlay: s_x/w1/b1 live only before the first barrier; z2 written after.
    float* const s_xf = (float*)s_ovl;                 // 4*256*4 = 4096 B
    float* const s_w1 = (float*)(s_ovl + 4096);        // 832 B
    float* const s_b1 = (float*)(s_ovl + 4928);        // 52 B
    unsigned char* const s_z2 = s_ovl;

    const int tid  = threadIdx.x;
    const int wave = tid >> 6, lane = tid & 63;
    const int quad = lane >> 4, col = lane & 15;

    // ---- stage x / w1 / b1 / wf / bf; zero both zimg buffers ----
    if (wave < 4)
        ((float4*)(s_xf + wave * 256))[lane] =
            ((const float4*)(x + (size_t)(blockIdx.x * 4 + wave) * 256))[lane];
    if (tid < 208) s_w1[tid] = w1[tid];
    if (tid < 13)  s_b1[tid] = b1[tid];
    for (int i = tid; i < 576; i += 384) {
        const int q = i >> 6, l = i & 63;
        ((float2*)s_wf)[i] = make_float2(wf[l * 9 + q], wf[576 + l * 9 + q]);
    }
    if (tid == 0) ((float2*)s_wf)[576] = make_float2(bf[0], bf[1]);
    for (int i = tid; i < 2 * ZIMG / 16; i += 384)
        ((uint4*)s_im)[i] = make_uint4(0, 0, 0, 0);
    __syncthreads();

    // ---- LIF1 row ownership: 312 rows = 4 samples * 13 ic * 6 y ----
    // waves 0-3: one row each (tid). waves 4,5: lanes 0-27 -> rows 256..311.
    const int rowi = (wave < 4) ? tid : (lane < 28 ? 256 + (wave - 4) * 28 + lane : -1);
    const bool rowv = rowi >= 0;
    int sA = 0, icA = 0, yA = 0;
    if (rowv) { sA = rowi / 78; int r = rowi - 78 * sA; icA = r / 6; yA = r - 6 * icA; }

    // conv1 output (time-constant): compute once, park in LDS (own-thread rd/wr)
    if (rowv) {
        float cu[6];
        conv1_row(s_xf + sA * 256, s_w1 + icA * 16, s_b1[icA], yA, cu);
        float2* cp = (float2*)(s_cur + rowi * 6);
        cp[0] = make_float2(cu[0], cu[1]);
        cp[1] = make_float2(cu[2], cu[3]);
        cp[2] = make_float2(cu[4], cu[5]);
    }
    float v1a[6], i1a[6];
    #pragma unroll
    for (int j = 0; j < 6; ++j) { v1a[j] = 0.f; i1a[j] = 0.f; }
    const int pbOffA = (9 * sA + 3 * yA) * IMSTRIDE + 16 * icA;

    // ---- A-fragments (waves 0-3 only): 3-level i8 split of w2 ----
    unsigned char* const a3p = s_a3 + (wave & 3) * 4096 + lane * 16;
    i32x4 A1[4] = {}, A2[4] = {};
    float Mrow = 1e-20f;
    float sc1[4] = {0.f, 0.f, 0.f, 0.f}, b2r[4] = {0.f, 0.f, 0.f, 0.f};
    if (wave < 4) {
        const float* wrow = w2 + (size_t)(wave * 16 + col) * 208;
        float M = 1e-20f;
        for (int k = 0; k < 208; ++k) M = fmaxf(M, fabsf(wrow[k]));
        Mrow = M;
        const float inv = 127.0f / M;
        const float q1s = M * (1.0f / 127.0f);
        const float q2s = M * (1.0f / (127.0f * 127.0f));
        #pragma unroll
        for (int kt = 0; kt < 4; ++kt) {
            i32x4 w1v = {0, 0, 0, 0}, w2v = {0, 0, 0, 0}, w3v = {0, 0, 0, 0};
            #pragma unroll
            for (int j = 0; j < 16; ++j) {
                const int kp = kt * 64 + quad * 16 + j;
                const int W = kp >> 2, kx = kp & 3;
                const int ic = W >> 2, ky = ((W & 3) - ic) & 3;
                const float w = (ic < 13) ? wrow[ic * 16 + ky * 4 + kx] : 0.f;
                const float b1f = rintf(w * inv);
                const float r1  = fmaf(b1f, -q1s, w);
                const float b2f = rintf(r1 * inv * 127.0f);
                const float r2  = fmaf(b2f, -q2s, r1);
                const float b3f = rintf(r2 * inv * 127.0f * 127.0f);
                const int wi = j >> 2, sh = (j & 3) * 8;
                w1v[wi] |= ((int)b1f & 0xFF) << sh;
                w2v[wi] |= ((int)b2f & 0xFF) << sh;
                w3v[wi] |= ((int)b3f & 0xFF) << sh;
            }
            A1[kt] = w1v; A2[kt] = w2v;
            *(i32x4*)(a3p + kt * 1024) = w3v;
        }
        #pragma unroll
        for (int r = 0; r < 4; ++r) {
            sc1[r] = __shfl(Mrow, quad * 4 + r) * (1.0f / 127.0f);
            b2r[r] = b2[wave * 16 + quad * 4 + r];
        }
    }

    int bpo[3], zwo[3];
    #pragma unroll
    for (int nt = 0; nt < 3; ++nt) {
        const int n = nt * 16 + col;            // 0..47, all rows exist in zimg
        bpo[nt] = n * IMSTRIDE + quad * 16;
        const int slz = n / 9, pos = n - 9 * slz;
        zwo[nt] = slz * 612 + pos * 68 + wave * 16 + quad * 4;
    }

    float v2[12], i2[12];
    #pragma unroll
    for (int p = 0; p < 12; ++p) { v2[p] = 0.f; i2[p] = 0.f; }

    // fc/LIF3 state (waves 4,5: two samples each)
    float v3a0 = 0.f, i3a0 = 0.f, v3b0 = 0.f, i3b0 = 0.f, s0a = 0.f, s0b = 0.f;
    float v3a1 = 0.f, i3a1 = 0.f, v3b1 = 0.f, i3b1 = 0.f, s1a = 0.f, s1b = 0.f;
    const int sfc = (wave - 4) * 2;            // valid for waves 4,5
    float* outv = out + (size_t)2 * B;

    // One fc + LIF3 step from a z2 sample base (u8), storing v3_seq[tp].
    auto fc_step = [&](const unsigned char* zs, int tp, int sG,
                       float& v3a, float& i3a, float& v3b, float& i3b,
                       float& su0, float& su1) {
        float p0 = 0.f, p1 = 0.f;
        #pragma unroll
        for (int q = 0; q < 9; ++q) {
            const float z = (float)zs[q * 68 + lane];
            const float2 wv = ((const float2*)s_wf)[q * 64 + lane];
            p0 = fmaf(z, wv.x, p0);
            p1 = fmaf(z, wv.y, p1);
        }
        #pragma unroll
        for (int off = 32; off > 0; off >>= 1) {
            p0 += __shfl_xor(p0, off);
            p1 += __shfl_xor(p1, off);
        }
        const float2 bfv = ((const float2*)s_wf)[576];
        const float c3a = p0 + bfv.x, c3b = p1 + bfv.y;
        const float vd0 = v3a + 0.1f * (i3a - v3a);
        const float vd1 = v3b + 0.1f * (i3b - v3b);
        i3a = i3a * 0.8f + c3a;
        i3b = i3b * 0.8f + c3b;
        const bool q0 = vd0 > 1.0f, q1 = vd1 > 1.0f;
        v3a = q0 ? 0.0f : vd0;
        v3b = q1 ? 0.0f : vd1;
        su0 += q0 ? 1.0f : 0.0f;
        su1 += q1 ? 1.0f : 0.0f;
        if (lane == 0)
            *(float2*)(outv + (size_t)tp * 2 * B + 2 * sG) = make_float2(v3a, v3b);
    };

    // LIF2 for one n-tile (static v2/i2 slices), returns packed spike bytes.
    auto lif2pack = [&](const i32x4 c1, const i32x4 c2, const i32x4 c3,
                        float* v2p, float* i2p) -> unsigned {
        unsigned zby = 0;
        #pragma unroll
        for (int r = 0; r < 4; ++r) {
            const float tt =
                fmaf(1.0f / (127.0f * 127.0f), (float)c3[r],
                fmaf(1.0f / 127.0f,            (float)c2[r],
                                               (float)c1[r]));
            const float cur2 = fmaf(sc1[r], tt, b2r[r]);
            const float vd = v2p[r] + 0.1f * (i2p[r] - v2p[r]);
            i2p[r] = i2p[r] * 0.8f + cur2;
            const bool sp = vd > 1.0f;
            v2p[r] = sp ? 0.0f : vd;
            zby |= (sp ? 1u : 0u) << (8 * r);
        }
        return zby;
    };

    // ---- main loop: 1 barrier/step; zimg ping-pong; fc on waves 4,5 lags 1 ----
    #pragma unroll 1
    for (int t = 0; t < NSTEPS; ++t) {
        unsigned char* zb = s_im + (t & 1) * ZIMG;
        if (rowv) {
            float cu[6];
            const float2* cp = (const float2*)(s_cur + rowi * 6);
            const float2 ca = cp[0], cb = cp[1], cc2 = cp[2];
            cu[0] = ca.x; cu[1] = ca.y; cu[2] = cb.x;
            cu[3] = cb.y; cu[4] = cc2.x; cu[5] = cc2.y;
            lif1_row(v1a, i1a, cu, zb + pbOffA, icA, yA);
        }
        __syncthreads();                 // the only barrier per step

        if (wave >= 4) {
            if (t) {  // deferred fc: step t-1 from ring slot (t-1)&3
                const unsigned char* zp = s_z2 + ((t - 1) & 3) * Z2SLOT;
                fc_step(zp + sfc * 612, t - 1, blockIdx.x * 4 + sfc,
                        v3a0, i3a0, v3b0, i3b0, s0a, s0b);
                fc_step(zp + (sfc + 1) * 612, t - 1, blockIdx.x * 4 + sfc + 1,
                        v3a1, i3a1, v3b1, i3b1, s1a, s1b);
            }
        } else {
            // GEMM + LIF2: serial n-tile passes, 3 chains live (12 acc regs)
            unsigned char* z2w = s_z2 + (t & 3) * Z2SLOT;
            #pragma unroll
            for (int nt = 0; nt < 3; ++nt) {
                i32x4 c1 = {0, 0, 0, 0}, c2 = c1, c3 = c1;
                __builtin_amdgcn_s_setprio(1);
                #pragma unroll
                for (int kt = 0; kt < 4; ++kt) {
                    const i32x4 Bv  = *(const i32x4*)(zb + bpo[nt] + kt * 64);
                    const i32x4 A3v = *(const i32x4*)(a3p + kt * 1024);
                    c1 = __builtin_amdgcn_mfma_i32_16x16x64_i8(A1[kt], Bv, c1, 0, 0, 0);
                    c2 = __builtin_amdgcn_mfma_i32_16x16x64_i8(A2[kt], Bv, c2, 0, 0, 0);
                    c3 = __builtin_amdgcn_mfma_i32_16x16x64_i8(A3v,    Bv, c3, 0, 0, 0);
                }
                __builtin_amdgcn_s_setprio(0);
                const unsigned pk = lif2pack(c1, c2, c3, &v2[nt * 4], &i2[nt * 4]);
                if (nt < 2 || col < 4)
                    *(unsigned*)(z2w + zwo[nt]) = pk;
            }
        }
    }

    __syncthreads();
    if (wave >= 4) {   // final fc: step 99 from slot 3
        const unsigned char* zp = s_z2 + ((NSTEPS - 1) & 3) * Z2SLOT;
        fc_step(zp + sfc * 612, NSTEPS - 1, blockIdx.x * 4 + sfc,
                v3a0, i3a0, v3b0, i3b0, s0a, s0b);
        fc_step(zp + (sfc + 1) * 612, NSTEPS - 1, blockIdx.x * 4 + sfc + 1,
                v3a1, i3a1, v3b1, i3b1, s1a, s1b);
        if (lane == 0) {
            *(float2*)(out + (size_t)2 * (blockIdx.x * 4 + sfc))     = make_float2(s0a, s0b);
            *(float2*)(out + (size_t)2 * (blockIdx.x * 4 + sfc + 1)) = make_float2(s1a, s1b);
        }
    }
}

extern "C" void kernel_launch(void* const* d_in, const int* in_sizes, int n_in,
                              void* d_out, int out_size, void* d_ws, size_t ws_size,
                              hipStream_t stream)
{
    const float* x  = (const float*)d_in[0];
    const float* w1 = (const float*)d_in[1];
    const float* b1 = (const float*)d_in[2];
    const float* w2 = (const float*)d_in[3];
    const float* b2 = (const float*)d_in[4];
    const float* wf = (const float*)d_in[5];
    const float* bf = (const float*)d_in[6];
    float* out = (float*)d_out;

    const int B = in_sizes[0] / 256;     // x is [B,1,16,16]
    const int grid = B / 4;              // 4 samples per block

    hipLaunchKernelGGL(snn_kernel, dim3(grid), dim3(384), 0, stream,
                       x, w1, b1, w2, b2, wf, bf, out, B);
}

// Round 7
// 259.491 us; speedup vs baseline: 1.4492x; 1.4453x over previous
//
#include <hip/hip_runtime.h>

// R15 = exact R8 (best verified: 231-268us this session) + integer Horner
// combine in LIF2. The R9-R14 occupancy arc is closed: wave slots quantize
// at combined(arch+acc) {<=64:8, <=128:4, <=256:2} per SIMD; this kernel
// needs ~160 combined, and every route under 128 either spills (R9/R11:
// allocator even-split strangles arch regs) or loses more to extra LDS
// round-trips than occupancy returns (R13/R14: 6-wave block -> 1 block/CU).
// Utilization scales linearly with resident waves (R8 8w vs R14 6w), so at
// 2 blocks/CU the pipes are unsaturated but the register cliff is
// unreachable -> optimize per-wave issue count on the R8 structure.
//  - LIF2 combine: ci = (c1*127 + c2)*127 + c3 via two __mul24 (range-safe:
//    |c1|<=26416<2^23, |c1*127+c2|<=3.38M<2^23, final <2^31), then ONE cvt +
//    ONE fma with sc3 = M/127^3. Replaces 3 cvt + 3 fma per r-slot; exact in
//    integer arithmetic (identical to the 3-scale sum up to float rounding).
//    Also retires sc1/sc2 arrays (-8 arch VGPRs).
// Everything else byte-identical to R8: Tc=2 chunking, 4 zimg buffers, bf16
// z2, 9-chain GEMM, per-wave fc. Numerics: 3-level nested i8, exact i32 acc.

#define NSTEPS 100
#define NCHUNK 50
#define IMSTRIDE 272
#define ZIMG (48 * IMSTRIDE)   // 13056 B per buffer; 4 buffers
#define Z2S 612                // shorts per (sample, step); 68-short pos stride
#define Z2T (4 * Z2S)          // shorts per t-slot
#define Z2PAR (2 * Z2T)        // shorts per chunk parity

typedef __attribute__((ext_vector_type(4))) int i32x4;

// conv1 + 2x2 maxpool for one spike-row (sample, ic, y): 6 outputs
__device__ __forceinline__ void conv1_row(const float* __restrict__ xs,
                                          const float* __restrict__ w1s,
                                          float b1v, int y, float* cur) {
    float cr[2][12];
    #pragma unroll
    for (int rr = 0; rr < 2; ++rr) {
        const int cy = 2 * y + rr;
        #pragma unroll
        for (int cx = 0; cx < 12; ++cx) {
            float a = 0.f;
            #pragma unroll
            for (int ky = 0; ky < 4; ++ky)
            #pragma unroll
            for (int kx = 0; kx < 4; ++kx)
                a = fmaf(xs[(cy + ky) * 16 + cx + kx], w1s[ky * 4 + kx], a);
            cr[rr][cx] = a + b1v;
        }
    }
    #pragma unroll
    for (int px = 0; px < 6; ++px)
        cur[px] = fmaxf(fmaxf(cr[0][2 * px], cr[0][2 * px + 1]),
                        fmaxf(cr[1][2 * px], cr[1][2 * px + 1]));
}

// LIF1 step for one spike-row + sigma-permuted i8 scatter (R7 layout).
// pb = zimg_buffer_base + (9*sl + 3*y)*IMSTRIDE + 16*ic
__device__ __forceinline__ void lif1_row(float* v1, float* i1, const float* cur,
                                         unsigned char* pb, int ic, int y) {
    unsigned zb[6];
    #pragma unroll
    for (int xx = 0; xx < 6; ++xx) {
        const float vd = v1[xx] + 0.1f * (i1[xx] - v1[xx]);
        i1[xx] = i1[xx] * 0.8f + cur[xx];
        const bool sp = vd > 1.0f;
        v1[xx] = sp ? 0.0f : vd;
        zb[xx] = sp ? 1u : 0u;
    }
    const unsigned q0 = zb[0] | (zb[1] << 8) | (zb[2] << 16) | (zb[3] << 24);
    const unsigned q1 = zb[1] | (zb[2] << 8) | (zb[3] << 16) | (zb[4] << 24);
    const unsigned q2 = zb[2] | (zb[3] << 8) | (zb[4] << 16) | (zb[5] << 24);
    #pragma unroll
    for (int ky = 0; ky < 4; ++ky) {
        const int py = y - ky;
        if (0 <= py && py <= 2) {
            unsigned char* b = pb - ky * (3 * IMSTRIDE) + 4 * ((ky + ic) & 3);
            *(unsigned*)(b)                = q0;   // px = 0
            *(unsigned*)(b + IMSTRIDE)     = q1;   // px = 1
            *(unsigned*)(b + 2 * IMSTRIDE) = q2;   // px = 2
        }
    }
}

__global__ __launch_bounds__(256, 2)
void snn_kernel(const float* __restrict__ x,
                const float* __restrict__ w1,
                const float* __restrict__ b1,
                const float* __restrict__ w2,
                const float* __restrict__ b2,
                const float* __restrict__ wf,
                const float* __restrict__ bf,
                float* __restrict__ out, int B)
{
    __shared__ __align__(16) unsigned char s_im[4 * ZIMG];       // 52224 B
    __shared__ __align__(16) unsigned short s_z2h[2 * Z2PAR];    // 19584 B
    __shared__ __align__(16) float s_x[4 * 256];                 // 4096 B
    __shared__ __align__(16) float s_w1[13 * 16];
    __shared__ float s_b1[13];

    const int tid  = threadIdx.x;
    const int wave = tid >> 6, lane = tid & 63;
    const int quad = lane >> 4, col = lane & 15;

    // ---- stage x / w1 / b1; zero all 4 zimg buffers ----
    ((float4*)(s_x + wave * 256))[lane] =
        ((const float4*)(x + (size_t)(blockIdx.x * 4 + wave) * 256))[lane];
    if (tid < 208) s_w1[tid] = w1[tid];
    if (tid < 13)  s_b1[tid] = b1[tid];
    for (int i = tid; i < 4 * ZIMG / 16; i += 256)
        ((uint4*)s_im)[i] = make_uint4(0, 0, 0, 0);
    __syncthreads();

    // ---- LIF1 row ownership: rows R = tid and tid+256 of 312 = 4*13*6 ----
    int sA, icA, yA, sB = 0, icB = 0, yB = 0;
    { const int R = tid;       sA = R / 78; int r = R - 78 * sA; icA = r / 6; yA = r - 6 * icA; }
    if (tid < 56) { const int R = tid + 256; sB = R / 78; int r = R - 78 * sB; icB = r / 6; yB = r - 6 * icB; }

    float cur1a[6], v1a[6], i1a[6], cur1b[6], v1b[6], i1b[6];
    conv1_row(s_x + sA * 256, s_w1 + icA * 16, s_b1[icA], yA, cur1a);
    if (tid < 56) conv1_row(s_x + sB * 256, s_w1 + icB * 16, s_b1[icB], yB, cur1b);
    #pragma unroll
    for (int j = 0; j < 6; ++j) { v1a[j] = i1a[j] = 0.f; v1b[j] = i1b[j] = 0.f; }

    const int pbOffA = (9 * sA + 3 * yA) * IMSTRIDE + 16 * icA;
    const int pbOffB = (9 * sB + 3 * yB) * IMSTRIDE + 16 * icB;

    // ---- A-fragments: per-row 3-level i8 split of w2 (sigma-permuted K) ----
    i32x4 A1[4], A2[4], A3[4];
    float Mrow;
    {
        const float* wrow = w2 + (size_t)(wave * 16 + col) * 208;
        float M = 1e-20f;
        for (int k = 0; k < 208; ++k) M = fmaxf(M, fabsf(wrow[k]));
        Mrow = M;
        const float inv = 127.0f / M;
        const float q1s = M * (1.0f / 127.0f);
        const float q2s = M * (1.0f / (127.0f * 127.0f));
        #pragma unroll
        for (int kt = 0; kt < 4; ++kt) {
            i32x4 w1v = {0, 0, 0, 0}, w2v = {0, 0, 0, 0}, w3v = {0, 0, 0, 0};
            #pragma unroll
            for (int j = 0; j < 16; ++j) {
                const int kp = kt * 64 + quad * 16 + j;
                const int W = kp >> 2, kx = kp & 3;
                const int ic = W >> 2, ky = ((W & 3) - ic) & 3;
                const float w = (ic < 13) ? wrow[ic * 16 + ky * 4 + kx] : 0.f;
                const float b1f = rintf(w * inv);
                const float r1  = fmaf(b1f, -q1s, w);
                const float b2f = rintf(r1 * inv * 127.0f);
                const float r2  = fmaf(b2f, -q2s, r1);
                const float b3f = rintf(r2 * inv * 127.0f * 127.0f);
                const int wi = j >> 2, sh = (j & 3) * 8;
                w1v[wi] |= ((int)b1f & 0xFF) << sh;
                w2v[wi] |= ((int)b2f & 0xFF) << sh;
                w3v[wi] |= ((int)b3f & 0xFF) << sh;
            }
            A1[kt] = w1v; A2[kt] = w2v; A3[kt] = w3v;
        }
    }
    // single per-lane scale: levels fold exactly via integer Horner combine
    float sc3[4];
    #pragma unroll
    for (int r = 0; r < 4; ++r) {
        const float Mr = __shfl(Mrow, quad * 4 + r);
        sc3[r] = Mr * (1.0f / (127.0f * 127.0f * 127.0f));
    }

    // ---- static per-lane: fc weights, b2, B-frag / z2 offsets ----
    float wf0[9], wf1[9];
    #pragma unroll
    for (int q = 0; q < 9; ++q) {
        wf0[q] = wf[lane * 9 + q];          // fc reads z2h[q*68 + lane] (oc=lane)
        wf1[q] = wf[576 + lane * 9 + q];
    }
    const float bfv0 = bf[0], bfv1 = bf[1];
    float b2r[4];
    #pragma unroll
    for (int r = 0; r < 4; ++r) b2r[r] = b2[wave * 16 + quad * 4 + r];

    int bpo[3];        // byte offset of B-frag within a zimg buffer
    int zwo[3];        // short offset of z2 write within a t-slot
    bool zv[3];
    #pragma unroll
    for (int nt = 0; nt < 3; ++nt) {
        const int n = nt * 16 + col;
        bpo[nt] = n * IMSTRIDE + quad * 16;
        zv[nt] = (n < 36);
        const int slz = n / 9, pos = n - slz * 9;
        zwo[nt] = slz * Z2S + pos * 68 + wave * 16 + quad * 4;
    }

    float v2[12], i2[12];
    #pragma unroll
    for (int p = 0; p < 12; ++p) { v2[p] = 0.f; i2[p] = 0.f; }
    float v3a = 0.f, i3a = 0.f, v3b = 0.f, i3b = 0.f, sum0 = 0.f, sum1 = 0.f;

    const int sG = blockIdx.x * 4 + wave;
    float* outv = out + (size_t)2 * B;

    // One fc + LIF3 step from a z2h t-slot base (shorts), storing v3_seq[tp].
    auto fc_step = [&](const unsigned short* zs, int tp) {
        float p0 = 0.f, p1 = 0.f;
        #pragma unroll
        for (int q = 0; q < 9; ++q) {
            const float z = __uint_as_float(((unsigned)zs[q * 68 + lane]) << 16);
            p0 = fmaf(z, wf0[q], p0);
            p1 = fmaf(z, wf1[q], p1);
        }
        #pragma unroll
        for (int off = 32; off > 0; off >>= 1) {
            p0 += __shfl_xor(p0, off);
            p1 += __shfl_xor(p1, off);
        }
        const float c3a = p0 + bfv0, c3b = p1 + bfv1;
        const float vd0 = v3a + 0.1f * (i3a - v3a);
        const float vd1 = v3b + 0.1f * (i3b - v3b);
        i3a = i3a * 0.8f + c3a;
        i3b = i3b * 0.8f + c3b;
        const bool q0 = vd0 > 1.0f, q1 = vd1 > 1.0f;
        v3a = q0 ? 0.0f : vd0;
        v3b = q1 ? 0.0f : vd1;
        sum0 += q0 ? 1.0f : 0.0f;
        sum1 += q1 ? 1.0f : 0.0f;
        if (lane == 0)
            *(float2*)(outv + (size_t)tp * 2 * B + 2 * sG) = make_float2(v3a, v3b);
    };

    // One chunk (2 timesteps), compile-time parity P at call sites.
    auto chunk = [&](int ch, int P) {
        // ---- Phase A: two LIF1 steps into zimg buffers 2P, 2P+1 ----
        unsigned char* zb0 = s_im + (2 * P) * ZIMG;
        unsigned char* zb1 = s_im + (2 * P + 1) * ZIMG;
        lif1_row(v1a, i1a, cur1a, zb0 + pbOffA, icA, yA);
        if (tid < 56) lif1_row(v1b, i1b, cur1b, zb0 + pbOffB, icB, yB);
        lif1_row(v1a, i1a, cur1a, zb1 + pbOffA, icA, yA);
        if (tid < 56) lif1_row(v1b, i1b, cur1b, zb1 + pbOffB, icB, yB);
        __syncthreads();                 // the only barrier per 2 steps

        // ---- deferred fc: both steps of chunk ch-1 (parity !P) ----
        if (ch) {
            const unsigned short* zp = s_z2h + (P ^ 1) * Z2PAR + wave * Z2S;
            fc_step(zp, 2 * ch - 2);
            fc_step(zp + Z2T, 2 * ch - 1);
        }

        // ---- GEMM + LIF2: two serial 9-chain passes ----
        #pragma unroll
        for (int tl = 0; tl < 2; ++tl) {
            const unsigned char* zbuf = s_im + (2 * P + tl) * ZIMG;
            i32x4 c1a = {0,0,0,0}, c1b = c1a, c1c = c1a;
            i32x4 c2a = c1a, c2b = c1a, c2c = c1a;
            i32x4 c3a_ = c1a, c3b_ = c1a, c3c = c1a;
            #pragma unroll
            for (int kt = 0; kt < 4; ++kt) {
                const i32x4 B0 = *(const i32x4*)(zbuf + bpo[0] + kt * 64);
                const i32x4 B1 = *(const i32x4*)(zbuf + bpo[1] + kt * 64);
                const i32x4 B2v = *(const i32x4*)(zbuf + bpo[2] + kt * 64);
                c1a = __builtin_amdgcn_mfma_i32_16x16x64_i8(A1[kt], B0,  c1a, 0, 0, 0);
                c1b = __builtin_amdgcn_mfma_i32_16x16x64_i8(A1[kt], B1,  c1b, 0, 0, 0);
                c1c = __builtin_amdgcn_mfma_i32_16x16x64_i8(A1[kt], B2v, c1c, 0, 0, 0);
                c2a = __builtin_amdgcn_mfma_i32_16x16x64_i8(A2[kt], B0,  c2a, 0, 0, 0);
                c2b = __builtin_amdgcn_mfma_i32_16x16x64_i8(A2[kt], B1,  c2b, 0, 0, 0);
                c2c = __builtin_amdgcn_mfma_i32_16x16x64_i8(A2[kt], B2v, c2c, 0, 0, 0);
                c3a_ = __builtin_amdgcn_mfma_i32_16x16x64_i8(A3[kt], B0,  c3a_, 0, 0, 0);
                c3b_ = __builtin_amdgcn_mfma_i32_16x16x64_i8(A3[kt], B1,  c3b_, 0, 0, 0);
                c3c = __builtin_amdgcn_mfma_i32_16x16x64_i8(A3[kt], B2v, c3c, 0, 0, 0);
            }

            const i32x4 L1[3] = {c1a, c1b, c1c};
            const i32x4 L2[3] = {c2a, c2b, c2c};
            const i32x4 L3[3] = {c3a_, c3b_, c3c};
            unsigned short* z2b = s_z2h + P * Z2PAR + tl * Z2T;
            #pragma unroll
            for (int nt = 0; nt < 3; ++nt) {
                unsigned zbits[4];
                #pragma unroll
                for (int r = 0; r < 4; ++r) {
                    const int p = nt * 4 + r;
                    // exact integer Horner: c1*127^2 + c2*127 + c3, then one
                    // cvt + one fma (ranges: |c1|<=26416, |t1|<=3.38M < 2^23)
                    const int t1 = __mul24(L1[nt][r], 127) + L2[nt][r];
                    const int ci = __mul24(t1, 127) + L3[nt][r];
                    const float cur2 = fmaf(sc3[r], (float)ci, b2r[r]);
                    const float vd = v2[p] + 0.1f * (i2[p] - v2[p]);
                    i2[p] = i2[p] * 0.8f + cur2;
                    const bool sp = vd > 1.0f;
                    v2[p] = sp ? 0.0f : vd;
                    zbits[r] = sp ? 0x3F80u : 0u;     // bf16 1.0
                }
                if (zv[nt]) {
                    const unsigned lo = zbits[0] | (zbits[1] << 16);
                    const unsigned hi = zbits[2] | (zbits[3] << 16);
                    *(uint2*)(z2b + zwo[nt]) = make_uint2(lo, hi);
                }
            }
        }
    };

    #pragma unroll 1
    for (int cc = 0; cc < NCHUNK; cc += 2) {
        chunk(cc, 0);
        chunk(cc + 1, 1);
    }

    __syncthreads();
    {   // final chunk (ch=49, P=1) fc
        const unsigned short* zp = s_z2h + 1 * Z2PAR + wave * Z2S;
        fc_step(zp, NSTEPS - 2);
        fc_step(zp + Z2T, NSTEPS - 1);
    }

    if (lane == 0)
        *(float2*)(out + (size_t)2 * sG) = make_float2(sum0, sum1);
}

extern "C" void kernel_launch(void* const* d_in, const int* in_sizes, int n_in,
                              void* d_out, int out_size, void* d_ws, size_t ws_size,
                              hipStream_t stream)
{
    const float* x  = (const float*)d_in[0];
    const float* w1 = (const float*)d_in[1];
    const float* b1 = (const float*)d_in[2];
    const float* w2 = (const float*)d_in[3];
    const float* b2 = (const float*)d_in[4];
    const float* wf = (const float*)d_in[5];
    const float* bf = (const float*)d_in[6];
    float* out = (float*)d_out;

    const int B = in_sizes[0] / 256;     // x is [B,1,16,16]
    const int grid = B / 4;              // 4 samples per block

    hipLaunchKernelGGL(snn_kernel, dim3(grid), dim3(256), 0, stream,
                       x, w1, b1, w2, b2, wf, bf, out, B);
}

// Round 8
// 259.132 us; speedup vs baseline: 1.4512x; 1.0014x over previous
//
#include <hip/hip_runtime.h>

// R16 = R15 (Horner LIF2, verified 220.6us rocprof) + fc restructuring.
// R15 post-mortem: counters calibrated per-CU (MfmaUtil 23% == predicted MFMA
// issue cycles). No pipe >50% -> dependency-latency-bound at 2 waves/SIMD.
// Biggest serial chain: 2x fc_step per chunk = 2x (6-level __shfl_xor
// butterfly, DS ~35cy/level, 2-wide) ~ 420cy dead time per chunk.
//  - fc_pair: both steps' dot-products first (4 independent partials), ONE
//    6-level butterfly with 4 interleaved chains (ILP hides DS latency),
//    then the two serial LIF3 updates (cheap VALU). ~210cy saved/chunk.
//  - fc moved to chunk TAIL (after GEMM): scheduling region GEMM -> fc ->
//    next LIF1 has no barrier, so shuffle-wait slots fill with LIF1 VALU.
//    Hazards: fc(ch) reads parity P^1 z2 (written by GEMM(ch-1), separated
//    by barrier(ch)); next writer GEMM(ch+1) is after barrier(ch+1), which
//    threads reach only after fc(ch) reads. Epilogue unchanged.
// Everything else identical to R15: Tc=2 chunks, 4 zimg buffers, bf16 z2,
// 9-chain GEMM, Horner combine, 3-level nested i8, exact i32 acc.

#define NSTEPS 100
#define NCHUNK 50
#define IMSTRIDE 272
#define ZIMG (48 * IMSTRIDE)   // 13056 B per buffer; 4 buffers
#define Z2S 612                // shorts per (sample, step); 68-short pos stride
#define Z2T (4 * Z2S)          // shorts per t-slot
#define Z2PAR (2 * Z2T)        // shorts per chunk parity

typedef __attribute__((ext_vector_type(4))) int i32x4;

// conv1 + 2x2 maxpool for one spike-row (sample, ic, y): 6 outputs
__device__ __forceinline__ void conv1_row(const float* __restrict__ xs,
                                          const float* __restrict__ w1s,
                                          float b1v, int y, float* cur) {
    float cr[2][12];
    #pragma unroll
    for (int rr = 0; rr < 2; ++rr) {
        const int cy = 2 * y + rr;
        #pragma unroll
        for (int cx = 0; cx < 12; ++cx) {
            float a = 0.f;
            #pragma unroll
            for (int ky = 0; ky < 4; ++ky)
            #pragma unroll
            for (int kx = 0; kx < 4; ++kx)
                a = fmaf(xs[(cy + ky) * 16 + cx + kx], w1s[ky * 4 + kx], a);
            cr[rr][cx] = a + b1v;
        }
    }
    #pragma unroll
    for (int px = 0; px < 6; ++px)
        cur[px] = fmaxf(fmaxf(cr[0][2 * px], cr[0][2 * px + 1]),
                        fmaxf(cr[1][2 * px], cr[1][2 * px + 1]));
}

// LIF1 step for one spike-row + sigma-permuted i8 scatter (R7 layout).
// pb = zimg_buffer_base + (9*sl + 3*y)*IMSTRIDE + 16*ic
__device__ __forceinline__ void lif1_row(float* v1, float* i1, const float* cur,
                                         unsigned char* pb, int ic, int y) {
    unsigned zb[6];
    #pragma unroll
    for (int xx = 0; xx < 6; ++xx) {
        const float vd = v1[xx] + 0.1f * (i1[xx] - v1[xx]);
        i1[xx] = i1[xx] * 0.8f + cur[xx];
        const bool sp = vd > 1.0f;
        v1[xx] = sp ? 0.0f : vd;
        zb[xx] = sp ? 1u : 0u;
    }
    const unsigned q0 = zb[0] | (zb[1] << 8) | (zb[2] << 16) | (zb[3] << 24);
    const unsigned q1 = zb[1] | (zb[2] << 8) | (zb[3] << 16) | (zb[4] << 24);
    const unsigned q2 = zb[2] | (zb[3] << 8) | (zb[4] << 16) | (zb[5] << 24);
    #pragma unroll
    for (int ky = 0; ky < 4; ++ky) {
        const int py = y - ky;
        if (0 <= py && py <= 2) {
            unsigned char* b = pb - ky * (3 * IMSTRIDE) + 4 * ((ky + ic) & 3);
            *(unsigned*)(b)                = q0;   // px = 0
            *(unsigned*)(b + IMSTRIDE)     = q1;   // px = 1
            *(unsigned*)(b + 2 * IMSTRIDE) = q2;   // px = 2
        }
    }
}

__global__ __launch_bounds__(256, 2)
void snn_kernel(const float* __restrict__ x,
                const float* __restrict__ w1,
                const float* __restrict__ b1,
                const float* __restrict__ w2,
                const float* __restrict__ b2,
                const float* __restrict__ wf,
                const float* __restrict__ bf,
                float* __restrict__ out, int B)
{
    __shared__ __align__(16) unsigned char s_im[4 * ZIMG];       // 52224 B
    __shared__ __align__(16) unsigned short s_z2h[2 * Z2PAR];    // 19584 B
    __shared__ __align__(16) float s_x[4 * 256];                 // 4096 B
    __shared__ __align__(16) float s_w1[13 * 16];
    __shared__ float s_b1[13];

    const int tid  = threadIdx.x;
    const int wave = tid >> 6, lane = tid & 63;
    const int quad = lane >> 4, col = lane & 15;

    // ---- stage x / w1 / b1; zero all 4 zimg buffers ----
    ((float4*)(s_x + wave * 256))[lane] =
        ((const float4*)(x + (size_t)(blockIdx.x * 4 + wave) * 256))[lane];
    if (tid < 208) s_w1[tid] = w1[tid];
    if (tid < 13)  s_b1[tid] = b1[tid];
    for (int i = tid; i < 4 * ZIMG / 16; i += 256)
        ((uint4*)s_im)[i] = make_uint4(0, 0, 0, 0);
    __syncthreads();

    // ---- LIF1 row ownership: rows R = tid and tid+256 of 312 = 4*13*6 ----
    int sA, icA, yA, sB = 0, icB = 0, yB = 0;
    { const int R = tid;       sA = R / 78; int r = R - 78 * sA; icA = r / 6; yA = r - 6 * icA; }
    if (tid < 56) { const int R = tid + 256; sB = R / 78; int r = R - 78 * sB; icB = r / 6; yB = r - 6 * icB; }

    float cur1a[6], v1a[6], i1a[6], cur1b[6], v1b[6], i1b[6];
    conv1_row(s_x + sA * 256, s_w1 + icA * 16, s_b1[icA], yA, cur1a);
    if (tid < 56) conv1_row(s_x + sB * 256, s_w1 + icB * 16, s_b1[icB], yB, cur1b);
    #pragma unroll
    for (int j = 0; j < 6; ++j) { v1a[j] = i1a[j] = 0.f; v1b[j] = i1b[j] = 0.f; }

    const int pbOffA = (9 * sA + 3 * yA) * IMSTRIDE + 16 * icA;
    const int pbOffB = (9 * sB + 3 * yB) * IMSTRIDE + 16 * icB;

    // ---- A-fragments: per-row 3-level i8 split of w2 (sigma-permuted K) ----
    i32x4 A1[4], A2[4], A3[4];
    float Mrow;
    {
        const float* wrow = w2 + (size_t)(wave * 16 + col) * 208;
        float M = 1e-20f;
        for (int k = 0; k < 208; ++k) M = fmaxf(M, fabsf(wrow[k]));
        Mrow = M;
        const float inv = 127.0f / M;
        const float q1s = M * (1.0f / 127.0f);
        const float q2s = M * (1.0f / (127.0f * 127.0f));
        #pragma unroll
        for (int kt = 0; kt < 4; ++kt) {
            i32x4 w1v = {0, 0, 0, 0}, w2v = {0, 0, 0, 0}, w3v = {0, 0, 0, 0};
            #pragma unroll
            for (int j = 0; j < 16; ++j) {
                const int kp = kt * 64 + quad * 16 + j;
                const int W = kp >> 2, kx = kp & 3;
                const int ic = W >> 2, ky = ((W & 3) - ic) & 3;
                const float w = (ic < 13) ? wrow[ic * 16 + ky * 4 + kx] : 0.f;
                const float b1f = rintf(w * inv);
                const float r1  = fmaf(b1f, -q1s, w);
                const float b2f = rintf(r1 * inv * 127.0f);
                const float r2  = fmaf(b2f, -q2s, r1);
                const float b3f = rintf(r2 * inv * 127.0f * 127.0f);
                const int wi = j >> 2, sh = (j & 3) * 8;
                w1v[wi] |= ((int)b1f & 0xFF) << sh;
                w2v[wi] |= ((int)b2f & 0xFF) << sh;
                w3v[wi] |= ((int)b3f & 0xFF) << sh;
            }
            A1[kt] = w1v; A2[kt] = w2v; A3[kt] = w3v;
        }
    }
    // single per-lane scale: levels fold exactly via integer Horner combine
    float sc3[4];
    #pragma unroll
    for (int r = 0; r < 4; ++r) {
        const float Mr = __shfl(Mrow, quad * 4 + r);
        sc3[r] = Mr * (1.0f / (127.0f * 127.0f * 127.0f));
    }

    // ---- static per-lane: fc weights, b2, B-frag / z2 offsets ----
    float wf0[9], wf1[9];
    #pragma unroll
    for (int q = 0; q < 9; ++q) {
        wf0[q] = wf[lane * 9 + q];          // fc reads z2h[q*68 + lane] (oc=lane)
        wf1[q] = wf[576 + lane * 9 + q];
    }
    const float bfv0 = bf[0], bfv1 = bf[1];
    float b2r[4];
    #pragma unroll
    for (int r = 0; r < 4; ++r) b2r[r] = b2[wave * 16 + quad * 4 + r];

    int bpo[3];        // byte offset of B-frag within a zimg buffer
    int zwo[3];        // short offset of z2 write within a t-slot
    bool zv[3];
    #pragma unroll
    for (int nt = 0; nt < 3; ++nt) {
        const int n = nt * 16 + col;
        bpo[nt] = n * IMSTRIDE + quad * 16;
        zv[nt] = (n < 36);
        const int slz = n / 9, pos = n - slz * 9;
        zwo[nt] = slz * Z2S + pos * 68 + wave * 16 + quad * 4;
    }

    float v2[12], i2[12];
    #pragma unroll
    for (int p = 0; p < 12; ++p) { v2[p] = 0.f; i2[p] = 0.f; }
    float v3a = 0.f, i3a = 0.f, v3b = 0.f, i3b = 0.f, sum0 = 0.f, sum1 = 0.f;

    const int sG = blockIdx.x * 4 + wave;
    float* outv = out + (size_t)2 * B;

    // fc + LIF3 for TWO consecutive steps: independent dot-products, one
    // 6-level butterfly with 4 interleaved chains, then serial LIF3 x2.
    auto fc_pair = [&](const unsigned short* zsA, int tpA,
                       const unsigned short* zsB, int tpB) {
        float p0a = 0.f, p1a = 0.f, p0b = 0.f, p1b = 0.f;
        #pragma unroll
        for (int q = 0; q < 9; ++q) {
            const float za = __uint_as_float(((unsigned)zsA[q * 68 + lane]) << 16);
            const float zb = __uint_as_float(((unsigned)zsB[q * 68 + lane]) << 16);
            p0a = fmaf(za, wf0[q], p0a);
            p1a = fmaf(za, wf1[q], p1a);
            p0b = fmaf(zb, wf0[q], p0b);
            p1b = fmaf(zb, wf1[q], p1b);
        }
        #pragma unroll
        for (int off = 32; off > 0; off >>= 1) {
            p0a += __shfl_xor(p0a, off);
            p1a += __shfl_xor(p1a, off);
            p0b += __shfl_xor(p0b, off);
            p1b += __shfl_xor(p1b, off);
        }
        // LIF3 step A
        {
            const float c3a = p0a + bfv0, c3b = p1a + bfv1;
            const float vd0 = v3a + 0.1f * (i3a - v3a);
            const float vd1 = v3b + 0.1f * (i3b - v3b);
            i3a = i3a * 0.8f + c3a;
            i3b = i3b * 0.8f + c3b;
            const bool q0 = vd0 > 1.0f, q1 = vd1 > 1.0f;
            v3a = q0 ? 0.0f : vd0;
            v3b = q1 ? 0.0f : vd1;
            sum0 += q0 ? 1.0f : 0.0f;
            sum1 += q1 ? 1.0f : 0.0f;
            if (lane == 0)
                *(float2*)(outv + (size_t)tpA * 2 * B + 2 * sG) = make_float2(v3a, v3b);
        }
        // LIF3 step B
        {
            const float c3a = p0b + bfv0, c3b = p1b + bfv1;
            const float vd0 = v3a + 0.1f * (i3a - v3a);
            const float vd1 = v3b + 0.1f * (i3b - v3b);
            i3a = i3a * 0.8f + c3a;
            i3b = i3b * 0.8f + c3b;
            const bool q0 = vd0 > 1.0f, q1 = vd1 > 1.0f;
            v3a = q0 ? 0.0f : vd0;
            v3b = q1 ? 0.0f : vd1;
            sum0 += q0 ? 1.0f : 0.0f;
            sum1 += q1 ? 1.0f : 0.0f;
            if (lane == 0)
                *(float2*)(outv + (size_t)tpB * 2 * B + 2 * sG) = make_float2(v3a, v3b);
        }
    };

    // One chunk (2 timesteps), compile-time parity P at call sites.
    auto chunk = [&](int ch, int P) {
        // ---- Phase A: two LIF1 steps into zimg buffers 2P, 2P+1 ----
        unsigned char* zb0 = s_im + (2 * P) * ZIMG;
        unsigned char* zb1 = s_im + (2 * P + 1) * ZIMG;
        lif1_row(v1a, i1a, cur1a, zb0 + pbOffA, icA, yA);
        if (tid < 56) lif1_row(v1b, i1b, cur1b, zb0 + pbOffB, icB, yB);
        lif1_row(v1a, i1a, cur1a, zb1 + pbOffA, icA, yA);
        if (tid < 56) lif1_row(v1b, i1b, cur1b, zb1 + pbOffB, icB, yB);
        __syncthreads();                 // the only barrier per 2 steps

        // ---- GEMM + LIF2: two serial 9-chain passes ----
        #pragma unroll
        for (int tl = 0; tl < 2; ++tl) {
            const unsigned char* zbuf = s_im + (2 * P + tl) * ZIMG;
            i32x4 c1a = {0,0,0,0}, c1b = c1a, c1c = c1a;
            i32x4 c2a = c1a, c2b = c1a, c2c = c1a;
            i32x4 c3a_ = c1a, c3b_ = c1a, c3c = c1a;
            #pragma unroll
            for (int kt = 0; kt < 4; ++kt) {
                const i32x4 B0 = *(const i32x4*)(zbuf + bpo[0] + kt * 64);
                const i32x4 B1 = *(const i32x4*)(zbuf + bpo[1] + kt * 64);
                const i32x4 B2v = *(const i32x4*)(zbuf + bpo[2] + kt * 64);
                c1a = __builtin_amdgcn_mfma_i32_16x16x64_i8(A1[kt], B0,  c1a, 0, 0, 0);
                c1b = __builtin_amdgcn_mfma_i32_16x16x64_i8(A1[kt], B1,  c1b, 0, 0, 0);
                c1c = __builtin_amdgcn_mfma_i32_16x16x64_i8(A1[kt], B2v, c1c, 0, 0, 0);
                c2a = __builtin_amdgcn_mfma_i32_16x16x64_i8(A2[kt], B0,  c2a, 0, 0, 0);
                c2b = __builtin_amdgcn_mfma_i32_16x16x64_i8(A2[kt], B1,  c2b, 0, 0, 0);
                c2c = __builtin_amdgcn_mfma_i32_16x16x64_i8(A2[kt], B2v, c2c, 0, 0, 0);
                c3a_ = __builtin_amdgcn_mfma_i32_16x16x64_i8(A3[kt], B0,  c3a_, 0, 0, 0);
                c3b_ = __builtin_amdgcn_mfma_i32_16x16x64_i8(A3[kt], B1,  c3b_, 0, 0, 0);
                c3c = __builtin_amdgcn_mfma_i32_16x16x64_i8(A3[kt], B2v, c3c, 0, 0, 0);
            }

            const i32x4 L1[3] = {c1a, c1b, c1c};
            const i32x4 L2[3] = {c2a, c2b, c2c};
            const i32x4 L3[3] = {c3a_, c3b_, c3c};
            unsigned short* z2b = s_z2h + P * Z2PAR + tl * Z2T;
            #pragma unroll
            for (int nt = 0; nt < 3; ++nt) {
                unsigned zbits[4];
                #pragma unroll
                for (int r = 0; r < 4; ++r) {
                    const int p = nt * 4 + r;
                    // exact integer Horner: c1*127^2 + c2*127 + c3, then one
                    // cvt + one fma (ranges: |c1|<=26416, |t1|<=3.38M < 2^23)
                    const int t1 = __mul24(L1[nt][r], 127) + L2[nt][r];
                    const int ci = __mul24(t1, 127) + L3[nt][r];
                    const float cur2 = fmaf(sc3[r], (float)ci, b2r[r]);
                    const float vd = v2[p] + 0.1f * (i2[p] - v2[p]);
                    i2[p] = i2[p] * 0.8f + cur2;
                    const bool sp = vd > 1.0f;
                    v2[p] = sp ? 0.0f : vd;
                    zbits[r] = sp ? 0x3F80u : 0u;     // bf16 1.0
                }
                if (zv[nt]) {
                    const unsigned lo = zbits[0] | (zbits[1] << 16);
                    const unsigned hi = zbits[2] | (zbits[3] << 16);
                    *(uint2*)(z2b + zwo[nt]) = make_uint2(lo, hi);
                }
            }
        }

        // ---- deferred fc at chunk TAIL: both steps of chunk ch-1 (P^1) ----
        // Reads separated from GEMM(ch-1) writes by barrier(ch); next writer
        // of those slots is GEMM(ch+1), after barrier(ch+1). The fc chain
        // overlaps with next-chunk LIF1 (no barrier between).
        if (ch) {
            const unsigned short* zp = s_z2h + (P ^ 1) * Z2PAR + wave * Z2S;
            fc_pair(zp, 2 * ch - 2, zp + Z2T, 2 * ch - 1);
        }
    };

    #pragma unroll 1
    for (int cc = 0; cc < NCHUNK; cc += 2) {
        chunk(cc, 0);
        chunk(cc + 1, 1);
    }

    __syncthreads();
    {   // final chunk (ch=49, P=1) fc
        const unsigned short* zp = s_z2h + 1 * Z2PAR + wave * Z2S;
        fc_pair(zp, NSTEPS - 2, zp + Z2T, NSTEPS - 1);
    }

    if (lane == 0)
        *(float2*)(out + (size_t)2 * sG) = make_float2(sum0, sum1);
}

extern "C" void kernel_launch(void* const* d_in, const int* in_sizes, int n_in,
                              void* d_out, int out_size, void* d_ws, size_t ws_size,
                              hipStream_t stream)
{
    const float* x  = (const float*)d_in[0];
    const float* w1 = (const float*)d_in[1];
    const float* b1 = (const float*)d_in[2];
    const float* w2 = (const float*)d_in[3];
    const float* b2 = (const float*)d_in[4];
    const float* wf = (const float*)d_in[5];
    const float* bf = (const float*)d_in[6];
    float* out = (float*)d_out;

    const int B = in_sizes[0] / 256;     // x is [B,1,16,16]
    const int grid = B / 4;              // 4 samples per block

    hipLaunchKernelGGL(snn_kernel, dim3(grid), dim3(256), 0, stream,
                       x, w1, b1, w2, b2, wf, bf, out, B);
}